// Round 5
// baseline (299.605 us; speedup 1.0000x reference)
//
#include <hip/hip_runtime.h>
#include <cstdint>
#include <math.h>

#define G 64
#define S 32
#define G3 (G*G*G)
#define S3 (S*S*S)

typedef unsigned long long u64;
typedef unsigned int u32;
typedef unsigned short u16;

typedef __attribute__((ext_vector_type(8))) short s16x8;   // 8 bf16 (4 VGPRs)
typedef __attribute__((ext_vector_type(4))) float f32x4;   // MFMA acc

#define ZPAD 4
#define ZSTR 72   // padded z stride (voxels)

__device__ __forceinline__ float sigmoidf_(float v) {
    return 1.0f / (1.0f + expf(-v));
}
__device__ __forceinline__ u32 f2bf_rne(float f) {   // round-to-nearest-even bf16
    u32 u = __float_as_uint(f);
    u += 0x7fff + ((u >> 16) & 1);
    return u >> 16;
}
__device__ __forceinline__ u64 rfl64(u64 v) {
    u32 lo = __builtin_amdgcn_readfirstlane((u32)v);
    u32 hi = __builtin_amdgcn_readfirstlane((u32)(v >> 32));
    return ((u64)hi << 32) | lo;
}
__device__ __forceinline__ u64 shiftw(u64 w, int dz) {   // dz compile-time after unroll
    return (dz >= 0) ? (w >> dz) : (w << (-dz));
}
// exact tap-usefulness: bits z where OUTPUT bit z set AND neighbor bit z+dz set
__device__ __forceinline__ u64 tap_hit(u64 wout, u64 wn, int dz) {
    return (dz >= 0) ? (wout & (wn >> dz)) : (wout & (wn << (-dz)));
}

// ---------------------------------------------------------------- parent occupancy
__global__ __launch_bounds__(256) void k_pocc(const float* __restrict__ x,
                                              unsigned char* __restrict__ pocc) {
    int p = blockIdx.x * 256 + threadIdx.x;
    if (p >= S3) return;
    int pz = p & 31, py = (p >> 5) & 31, px = p >> 10;
    const float* b = x + (((size_t)(px * 2) * G + py * 2) * G + pz * 2);
    bool occ = false;
    #pragma unroll
    for (int a = 0; a < 2; a++)
        #pragma unroll
        for (int bb = 0; bb < 2; bb++)
            #pragma unroll
            for (int c = 0; c < 2; c++)
                occ = occ || (b[((size_t)a * G + bb) * G + c] > 0.0f);
    pocc[p] = occ ? 1 : 0;
}

// ---------------------------------------------------------------- FEL conv1: 1->16, 3^3, relu
__global__ __launch_bounds__(256) void k_fel1(const unsigned char* __restrict__ pocc,
                                              const float* __restrict__ w1,
                                              const float* __restrict__ b1,
                                              float* __restrict__ h1) {
    int p = blockIdx.x * 256 + threadIdx.x;
    if (p >= S3) return;
    int pz = p & 31, py = (p >> 5) & 31, px = p >> 10;
    float* o = h1 + (size_t)p * 16;
    if (!pocc[p]) {
        #pragma unroll
        for (int i = 0; i < 16; i++) o[i] = 0.0f;
        return;
    }
    float acc[16];
    #pragma unroll
    for (int i = 0; i < 16; i++) acc[i] = b1[i];
    for (int dx = -1; dx <= 1; ++dx) {
        int nx = px + dx; if ((unsigned)nx >= S) continue;
        for (int dy = -1; dy <= 1; ++dy) {
            int ny = py + dy; if ((unsigned)ny >= S) continue;
            for (int dz = -1; dz <= 1; ++dz) {
                int nz = pz + dz; if ((unsigned)nz >= S) continue;
                if (pocc[(nx * S + ny) * S + nz]) {
                    const float* w = w1 + (((dx + 1) * 3 + (dy + 1)) * 3 + (dz + 1)) * 16;
                    #pragma unroll
                    for (int i = 0; i < 16; i++) acc[i] += w[i];
                }
            }
        }
    }
    #pragma unroll
    for (int i = 0; i < 16; i++) o[i] = fmaxf(acc[i], 0.0f);
}

// ---------------------------------------------------------------- FEL conv2: 16->16, 3^3
__global__ __launch_bounds__(256) void k_fel2(const unsigned char* __restrict__ pocc,
                                              const float* __restrict__ h1,
                                              const float* __restrict__ w2,
                                              const float* __restrict__ b2,
                                              float* __restrict__ h2) {
    int p = blockIdx.x * 256 + threadIdx.x;
    if (p >= S3) return;
    int pz = p & 31, py = (p >> 5) & 31, px = p >> 10;
    float* o = h2 + (size_t)p * 16;
    if (!pocc[p]) {
        #pragma unroll
        for (int i = 0; i < 16; i++) o[i] = 0.0f;
        return;
    }
    float acc[16];
    #pragma unroll
    for (int i = 0; i < 16; i++) acc[i] = b2[i];
    for (int dx = -1; dx <= 1; ++dx) {
        int nx = px + dx; if ((unsigned)nx >= S) continue;
        for (int dy = -1; dy <= 1; ++dy) {
            int ny = py + dy; if ((unsigned)ny >= S) continue;
            for (int dz = -1; dz <= 1; ++dz) {
                int nz = pz + dz; if ((unsigned)nz >= S) continue;
                const float* f = h1 + (size_t)((nx * S + ny) * S + nz) * 16;
                const float* w = w2 + (((dx + 1) * 3 + (dy + 1)) * 3 + (dz + 1)) * 256;
                #pragma unroll
                for (int ci = 0; ci < 16; ++ci) {
                    float fv = f[ci];
                    #pragma unroll
                    for (int co = 0; co < 16; ++co)
                        acc[co] = fmaf(fv, w[ci * 16 + co], acc[co]);
                }
            }
        }
    }
    #pragma unroll
    for (int i = 0; i < 16; i++) o[i] = acc[i];
}

// ---------------------------------------------------------------- generative up (k2 s2) -> prob_f (bf16, z-padded stride 72)
__global__ __launch_bounds__(256) void k_up(const unsigned char* __restrict__ pocc,
                                            const float* __restrict__ h2,
                                            const float* __restrict__ wup,
                                            const float* __restrict__ bup,
                                            u16* __restrict__ pf) {
    int p = blockIdx.x * 256 + threadIdx.x;
    if (p >= S3) return;
    int pz = p & 31, py = (p >> 5) & 31, px = p >> 10;
    bool occ = pocc[p] != 0;
    float h[16];
    const float* hp = h2 + (size_t)p * 16;
    #pragma unroll
    for (int i = 0; i < 16; i++) h[i] = hp[i];
    #pragma unroll
    for (int o = 0; o < 8; o++) {
        int a = o >> 2, b = (o >> 1) & 1, c = o & 1;
        u16* op = pf + (((size_t)(2 * px + a) * G + (2 * py + b)) * ZSTR + (2 * pz + c) + ZPAD) * 16;
        uint4* o4 = reinterpret_cast<uint4*>(op);
        if (!occ) {
            o4[0] = make_uint4(0, 0, 0, 0);
            o4[1] = make_uint4(0, 0, 0, 0);
        } else {
            u32 pk[8];
            #pragma unroll
            for (int i = 0; i < 8; ++i) {
                float a0 = bup[2 * i], a1 = bup[2 * i + 1];
                #pragma unroll
                for (int cc = 0; cc < 16; cc++) {
                    a0 = fmaf(h[cc], wup[(o * 16 + cc) * 16 + 2 * i], a0);
                    a1 = fmaf(h[cc], wup[(o * 16 + cc) * 16 + 2 * i + 1], a1);
                }
                pk[i] = f2bf_rne(a0) | (f2bf_rne(a1) << 16);
            }
            o4[0] = make_uint4(pk[0], pk[1], pk[2], pk[3]);
            o4[1] = make_uint4(pk[4], pk[5], pk[6], pk[7]);
        }
    }
    // zero z-pad zones of the 4 child lines owned by (px,py,*): done by pz==0 threads
    if (pz == 0) {
        uint4 zz = make_uint4(0, 0, 0, 0);
        #pragma unroll
        for (int a = 0; a < 2; a++)
            #pragma unroll
            for (int b = 0; b < 2; b++) {
                u16* lp = pf + ((size_t)((2 * px + a) * G + (2 * py + b)) * ZSTR) * 16;
                #pragma unroll
                for (int q = 0; q < ZPAD; q++) {
                    *reinterpret_cast<uint4*>(lp + q * 16) = zz;
                    *reinterpret_cast<uint4*>(lp + q * 16 + 8) = zz;
                    *reinterpret_cast<uint4*>(lp + (G + ZPAD + q) * 16) = zz;
                    *reinterpret_cast<uint4*>(lp + (G + ZPAD + q) * 16 + 8) = zz;
                }
            }
    }
}

// ---------------------------------------------------------------- masks -> 64-bit line words + labels
__global__ __launch_bounds__(256) void k_masks(const float* __restrict__ x,
                                               const unsigned char* __restrict__ pocc,
                                               u64* __restrict__ lw_in,
                                               u64* __restrict__ lw_fin,
                                               float* __restrict__ labels) {
    int z = threadIdx.x;
    int y = blockIdx.x * 4 + threadIdx.y;
    int xx = blockIdx.y;
    int v = (xx * G + y) * G + z;
    int par = ((xx & 1) << 2) | ((y & 1) << 1) | (z & 1);
    const int gmap[8] = {0, 5, 4, 3, 4, 2, 1, 5};
    int g = gmap[par];
    int t = ((xx >> 1) + (y >> 1) + (z >> 1)) % 3;
    bool occ = pocc[(((xx >> 1) * S) + (y >> 1)) * S + (z >> 1)] != 0;
    bool ox = x[v] > 0.0f;
    bool g0 = (g == 0);

    bool mi[8], mf[8], lb[8];
    mi[0] = occ && g0 && (t == 0);
    mi[1] = (occ && g0 && (t == 1)) || (ox && g0 && (t == 0));
    mi[2] = (ox && g0 && (t < 2)) || (occ && g0 && (t == 2));
    mi[3] = (ox && g0)       || (occ && (g == 1));
    mi[4] = (ox && (g <= 1)) || (occ && (g == 2));
    mi[5] = (ox && (g <= 2)) || (occ && (g == 3));
    mi[6] = (ox && (g <= 3)) || (occ && (g == 4));
    mi[7] = (ox && (g <= 4)) || (occ && (g == 5));

    mf[0] = occ && g0 && (t == 0);
    mf[1] = occ && g0 && (t == 1);
    mf[2] = occ && g0 && (t == 2);
    mf[3] = occ && (g == 1);
    mf[4] = occ && (g == 2);
    mf[5] = occ && (g == 3);
    mf[6] = occ && (g == 4);
    mf[7] = occ && (g == 5);

    lb[0] = ox && g0 && (t == 0);
    lb[1] = ox && g0 && (t == 1);
    lb[2] = ox && g0 && (t == 2);
    lb[3] = ox && (g == 1);
    lb[4] = ox && (g == 2);
    lb[5] = ox && (g == 3);
    lb[6] = ox && (g == 4);
    lb[7] = ox && (g == 5);

    int line = xx * G + y;
    #pragma unroll
    for (int c = 0; c < 8; ++c) {
        u64 wi = __ballot((int)mi[c]);
        u64 wf = __ballot((int)mf[c]);
        if (z == 0) {
            lw_in[c * 4096 + line] = wi;
            lw_fin[c * 4096 + line] = wf;
        }
        labels[(size_t)c * G3 + v] = lb[c] ? 1.0f : 0.0f;
    }
}

// ---------------------------------------------------------------- B-fragment prep (weights -> MFMA lane layout, bf16)
// frag index = ((dxi*KS)+dyi)*npair + p ; k<16 -> dz_A = -R+2p ; k>=16 -> dz_B = dz_A+1 (zero if OOB)
#define FRAGSTRIDE 38400   // u16 per coder (75 frags * 64 lanes * 8)
__global__ __launch_bounds__(64) void k_prep_bfrag(const float* __restrict__ wc1,
                                                   const float* __restrict__ wl1,
                                                   u16* __restrict__ bfrag) {
    int c = blockIdx.x;
    int frag = blockIdx.y;
    int lane = threadIdx.x;
    bool is5 = (c == 1 || c == 2);
    int R = is5 ? 2 : 1;
    int KS = 2 * R + 1;
    int npair = R + 1;
    int nfrag = KS * KS * npair;
    if (frag >= nfrag) return;
    const float* W = is5 ? (wl1 + (size_t)(c - 1) * 32000)
                         : (wc1 + (size_t)((c == 0) ? 0 : (c - 2)) * 6912);
    int dxdy = frag / npair, p = frag - dxdy * npair;
    int dxi = dxdy / KS, dyi = dxdy - dxi * KS;
    int dziA = 2 * p, dziB = 2 * p + 1;
    int co = lane & 15, kg = lane >> 4;
    u16 outv[8];
    #pragma unroll
    for (int j = 0; j < 8; ++j) {
        int k = kg * 8 + j;
        int ci = k & 15;
        int dzi = (k < 16) ? dziA : dziB;
        float v = 0.0f;
        if (dzi < KS)
            v = W[(size_t)((dxi * KS + dyi) * KS + dzi) * 256 + ci * 16 + co];
        outv[j] = (u16)f2bf_rne(v);
    }
    u16* o = bfrag + (size_t)c * FRAGSTRIDE + ((size_t)frag * 64 + lane) * 8;
    uint4 pk;
    pk.x = outv[0] | ((u32)outv[1] << 16);
    pk.y = outv[2] | ((u32)outv[3] << 16);
    pk.z = outv[4] | ((u32)outv[5] << 16);
    pk.w = outv[6] | ((u32)outv[7] << 16);
    *reinterpret_cast<uint4*>(o) = pk;
}

// ---------------------------------------------------------------- conv1 via MFMA, direct-global A-reads (no LDS, no barriers)
// wave = one output z-line. A-frag: lane reads 16B of voxel (z=s*16+(l&15)+dz) half (kg&1)
// from the z-padded probf16; masked-off voxels zeroed in-register via per-lane bit test.
template <int R>
__device__ __forceinline__ void conv1_mfma_body(const u16* __restrict__ pf,
                                                const u64* __restrict__ lw,
                                                const u16* __restrict__ bf,
                                                const float* __restrict__ bptr,
                                                u16* __restrict__ h_c) {
    const int KS = 2 * R + 1, NP = R + 1;
    int lane = threadIdx.x;
    int line = blockIdx.x * 4 + threadIdx.y;
    int x = line >> 6, y = line & 63;

    u64 w0 = rfl64(lw[line]);
    if (w0 == 0ULL) return;

    int m = lane & 15, kg = lane >> 4, half = kg & 1;
    float bv = bptr[m];
    f32x4 acc[4];
    #pragma unroll
    for (int s = 0; s < 4; ++s) acc[s] = (f32x4){bv, bv, bv, bv};
    const s16x8 zf = {};

    for (int dx = -R; dx <= R; ++dx) {
        int nx = x + dx;
        if ((unsigned)nx >= G) continue;
        u64 wrow[KS];
        #pragma unroll
        for (int dy = -R; dy <= R; ++dy) {
            int ny = y + dy;
            wrow[dy + R] = ((unsigned)ny < G) ? rfl64(lw[nx * G + ny]) : 0ULL;
        }
        #pragma unroll
        for (int dy = -R; dy <= R; ++dy) {
            u64 wn = wrow[dy + R];
            if (wn == 0ULL) continue;
            int ny = y + dy;
            const u16* nb = pf + ((size_t)(nx * G + ny)) * ZSTR * 16;
            #pragma unroll
            for (int p = 0; p < NP; ++p) {
                const int dzA = -R + 2 * p;
                const int dzB = dzA + 1;
                const bool hasB = (dzB <= R);
                u64 wshA = shiftw(wn, dzA);
                u64 wshB = hasB ? shiftw(wn, dzB) : wshA;
                u64 hit = (w0 & wshA) | (hasB ? (w0 & wshB) : 0ULL);
                if (hit == 0ULL) continue;
                int frag = ((dx + R) * KS + (dy + R)) * NP + p;
                s16x8 b8 = *reinterpret_cast<const s16x8*>(bf + ((size_t)frag * 64 + lane) * 8);
                u64 wsh_l = (kg < 2) ? wshA : wshB;
                int dz_l = (kg < 2) ? dzA : (hasB ? dzB : dzA);
                const u16* ab = nb + (size_t)(ZPAD + dz_l + m) * 16 + half * 8;
                #pragma unroll
                for (int s = 0; s < 4; ++s) {
                    if (((hit >> (s * 16)) & 0xFFFFULL) == 0ULL) continue;
                    s16x8 a = *reinterpret_cast<const s16x8*>(ab + s * 256);
                    u32 mb = (u32)(wsh_l >> (s * 16 + m)) & 1u;
                    a = mb ? a : zf;
                    acc[s] = __builtin_amdgcn_mfma_f32_16x16x32_bf16(a, b8, acc[s], 0, 0, 0);
                }
            }
        }
    }

    u16* hline = h_c + (size_t)line * G * 16;
    #pragma unroll
    for (int s = 0; s < 4; ++s) {
        #pragma unroll
        for (int r = 0; r < 4; ++r) {
            int z = s * 16 + kg * 4 + r;
            if ((w0 >> z) & 1) {
                float v = fmaxf(acc[s][r], 0.0f);
                hline[z * 16 + m] = (u16)f2bf_rne(v);
            }
        }
    }
}

__global__ __launch_bounds__(256) void k_conv1_mfma(const u16* __restrict__ pf,
                                                    const u64* __restrict__ lw_in,
                                                    const u16* __restrict__ bfrag,
                                                    const float* __restrict__ bc1,
                                                    const float* __restrict__ bl1,
                                                    u16* __restrict__ hbase,
                                                    int coderBase) {
    int c = coderBase + blockIdx.y;
    const u64* lw = lw_in + (size_t)c * 4096;
    u16* h_c = hbase + (size_t)blockIdx.y * G3 * 16;
    const u16* bf = bfrag + (size_t)c * FRAGSTRIDE;
    if (c == 1 || c == 2) {
        conv1_mfma_body<2>(pf, lw, bf, bl1 + (c - 1) * 16, h_c);
    } else {
        int j = (c == 0) ? 0 : (c - 2);
        conv1_mfma_body<1>(pf, lw, bf, bc1 + j * 16, h_c);
    }
}

// ---------------------------------------------------------------- coder conv2 body (C->1, K^3, sigmoid) — unchanged
template <int KS>
__device__ __forceinline__ void conv2_body(const u32* __restrict__ h_c,
                                           const u64* __restrict__ lwi,
                                           const u64* __restrict__ lwf,
                                           const float* __restrict__ w2,
                                           const float* __restrict__ b2,
                                           float* __restrict__ outp) {
    const int R = KS / 2;
    int z = threadIdx.x;
    int line = blockIdx.x * 4 + threadIdx.y;
    int xx = line >> 6, y = line & 63;
    int v = (xx * G + y) * G + z;
    u64 wf = rfl64(lwf[line]);
    if (wf == 0ULL) { outp[v] = 0.0f; return; }
    bool m = (wf >> z) & 1;

    float acc = b2[0];
    for (int dx = -R; dx <= R; ++dx) {
        int nx = xx + dx; if ((unsigned)nx >= G) continue;
        for (int dy = -R; dy <= R; ++dy) {
            int ny = y + dy; if ((unsigned)ny >= G) continue;
            u64 wn = rfl64(lwi[nx * G + ny]);
            if (wn == 0ULL) continue;
            const float* wbase = w2 + (size_t)(((dx + R) * KS + (dy + R)) * KS) * 16;
            #pragma unroll
            for (int dz = -R; dz <= R; ++dz) {
                if (tap_hit(wf, wn, dz) == 0ULL) continue;
                int nz = z + dz;
                bool ok = (unsigned)nz < G;
                int nzc = ok ? nz : 0;
                bool mn = ok && ((wn >> nzc) & 1);
                const float* w = wbase + (dz + R) * 16;
                if (mn) {
                    const uint4* h4 = reinterpret_cast<const uint4*>(
                        h_c + ((size_t)((nx * G + ny) * G + nzc)) * 8);
                    uint4 Ua = h4[0], Ub = h4[1];
                    u32 uu[8] = {Ua.x, Ua.y, Ua.z, Ua.w, Ub.x, Ub.y, Ub.z, Ub.w};
                    #pragma unroll
                    for (int i = 0; i < 8; ++i) {
                        float lo = __uint_as_float(uu[i] << 16);
                        float hi = __uint_as_float(uu[i] & 0xffff0000u);
                        acc = fmaf(lo, w[2 * i], acc);
                        acc = fmaf(hi, w[2 * i + 1], acc);
                    }
                }
            }
        }
    }
    outp[v] = m ? sigmoidf_(acc) : 0.0f;
}

__global__ __launch_bounds__(256) void k_conv2_all(const u32* __restrict__ hbase,
                                                   const u64* __restrict__ lw_in,
                                                   const u64* __restrict__ lw_fin,
                                                   const float* __restrict__ wc2,
                                                   const float* __restrict__ bc2,
                                                   const float* __restrict__ wl2,
                                                   const float* __restrict__ bl2,
                                                   float* __restrict__ out,
                                                   int coderBase) {
    int c = coderBase + blockIdx.y;
    const u64* lwi = lw_in + (size_t)c * 4096;
    const u64* lwf = lw_fin + (size_t)c * 4096;
    const u32* h_c = hbase + (size_t)blockIdx.y * G3 * 8;
    float* outp = out + (size_t)c * G3;
    if (c == 1 || c == 2) {
        conv2_body<5>(h_c, lwi, lwf, wl2 + (size_t)(c - 1) * 2000, bl2 + (c - 1), outp);
    } else {
        int j = (c == 0) ? 0 : (c - 2);
        conv2_body<3>(h_c, lwi, lwf, wc2 + (size_t)j * 432, bc2 + j, outp);
    }
}

// ---------------------------------------------------------------- launch
extern "C" void kernel_launch(void* const* d_in, const int* in_sizes, int n_in,
                              void* d_out, int out_size, void* d_ws, size_t ws_size,
                              hipStream_t stream) {
    const float* x      = (const float*)d_in[0];
    const float* w_fel1 = (const float*)d_in[3];
    const float* b_fel1 = (const float*)d_in[4];
    const float* w_fel2 = (const float*)d_in[5];
    const float* b_fel2 = (const float*)d_in[6];
    const float* w_up   = (const float*)d_in[7];
    const float* b_up   = (const float*)d_in[8];
    const float* wc1    = (const float*)d_in[9];
    const float* bc1    = (const float*)d_in[10];
    const float* wc2    = (const float*)d_in[11];
    const float* bc2    = (const float*)d_in[12];
    const float* wl1    = (const float*)d_in[13];
    const float* bl1    = (const float*)d_in[14];
    const float* wl2    = (const float*)d_in[15];
    const float* bl2    = (const float*)d_in[16];
    float* out = (float*)d_out;

    char* ws = (char*)d_ws;
    u16*  probf16 = (u16*)(ws);                            // 9.44 MB  bf16[4096][72][16] z-padded
    float* h1     = (float*)(ws + 9437184);                // 2 MB
    float* h2     = (float*)(ws + 11534336);               // 2 MB
    unsigned char* pocc = (unsigned char*)(ws + 13631488); // 32 KB
    u64* lw_in  = (u64*)(ws + 13664256);                   // 256 KB
    u64* lw_fin = (u64*)(ws + 13926400);                   // 256 KB
    u16* bfrag  = (u16*)(ws + 14188544);                   // 600 KB
    u16* hbase  = (u16*)(ws + 14802944);                   // B * 8 MB (bf16 h)

    const size_t fixed_end = 14802944;
    const size_t hsz = (size_t)G3 * 16 * 2;                // 8 MB per coder
    int B = 2;
    if (fixed_end + 8 * hsz <= ws_size) B = 8;
    else if (fixed_end + 4 * hsz <= ws_size) B = 4;

    k_pocc <<<dim3(S3 / 256), dim3(256), 0, stream>>>(x, pocc);
    k_fel1 <<<dim3(S3 / 256), dim3(256), 0, stream>>>(pocc, w_fel1, b_fel1, h1);
    k_fel2 <<<dim3(S3 / 256), dim3(256), 0, stream>>>(pocc, h1, w_fel2, b_fel2, h2);
    k_up   <<<dim3(S3 / 256), dim3(256), 0, stream>>>(pocc, h2, w_up, b_up, probf16);
    k_masks<<<dim3(16, 64), dim3(64, 4), 0, stream>>>(x, pocc, lw_in, lw_fin, out + (size_t)8 * G3);
    k_prep_bfrag<<<dim3(8, 75), dim3(64), 0, stream>>>(wc1, wl1, bfrag);

    for (int b0 = 0; b0 < 8; b0 += B) {
        int nb = (8 - b0 < B) ? (8 - b0) : B;
        k_conv1_mfma<<<dim3(1024, nb), dim3(64, 4), 0, stream>>>(
            probf16, lw_in, bfrag, bc1, bl1, hbase, b0);
        k_conv2_all<<<dim3(1024, nb), dim3(64, 4), 0, stream>>>(
            (const u32*)hbase, lw_in, lw_fin, wc2, bc2, wl2, bl2, out, b0);
    }
}